// Round 5
// baseline (8445.673 us; speedup 1.0000x reference)
//
#include <hip/hip_runtime.h>
#include <hip/hip_bf16.h>
#include <stdint.h>

// Problem constants (from reference)
#define S_WORDS 2048
#define LMAX    16
#define CE      256
#define WE      512
#define HDIM    1024
#define GC      1024   // 4*CE
#define GW      4096   // 4*HDIM
#define KW      768    // WE + CE
#define NWG     128    // persistent workgroups for word recurrence

// Workspace layout (bytes) — high-water 50,331,648 (48 MiB)
#define IN_GATES_OFF 0                       // 2048*4096 fp32 = 33554432
#define LAST_OFF     33554432                // 2048*256 fp32  =  2097152
#define WT2C_OFF     35651584                // 256*1024 float2 = 2097152 (char weights)
#define WT2W_OFF     37748736                // 384*4096 float2 = 12582912
// Ring aliases WT2c (dead after char_lstm; memset enqueued after char_lstm):
#define RING_OFF     WT2C_OFF                // 3 slots * 1024 u64 = 24576

typedef float f32x4 __attribute__((ext_vector_type(4)));

static __device__ __forceinline__ float sigm(float x) { return 1.0f / (1.0f + __expf(-x)); }
// fast tanh: (e^{2|x|}-1)/(e^{2|x|}+1) with sign restore; clamp avoids inf/inf
static __device__ __forceinline__ float tanh_fast(float x) {
    float ax = fminf(fabsf(x), 15.0f);
    float e  = __expf(2.0f * ax);
    float t  = (e - 1.0f) / (e + 1.0f);
    return copysignf(t, x);
}

// ---------- prep: transposed k-major float2 pairs for coalesced reads ----------
__global__ void prep_c_kernel(const float* __restrict__ Wih,
                              const float* __restrict__ Whh,
                              float2* __restrict__ WT2c) {
    int idx = blockIdx.x * blockDim.x + threadIdx.x;   // 256*1024
    if (idx >= 256 * GC) return;
    int kp = idx >> 10, row = idx & (GC - 1);
    int k = kp * 2;
    float2 v;
    if (k < CE) { v.x = Wih[row * CE + k];      v.y = Wih[row * CE + k + 1]; }
    else        { v.x = Whh[row * CE + k - CE]; v.y = Whh[row * CE + k - CE + 1]; }
    WT2c[idx] = v;
}

__global__ void prep_w_kernel(const float* __restrict__ Wih,
                              float2* __restrict__ WT2w) {
    int idx = blockIdx.x * blockDim.x + threadIdx.x;   // 384*4096
    if (idx >= 384 * GW) return;
    int kp = idx >> 12, row = idx & (GW - 1);
    float2 v;
    v.x = Wih[row * KW + 2 * kp];
    v.y = Wih[row * KW + 2 * kp + 1];
    WT2w[idx] = v;
}

// ---------- char LSTM: 256 blocks x 256 threads; block handles 8 words ----------
__global__ void __launch_bounds__(256) char_lstm_kernel(
    const int* __restrict__ char_idxs,        // [2048][16]
    const int* __restrict__ char_lens,        // [2048]
    const float* __restrict__ char_emb,       // [256][256]
    const float* __restrict__ bih,            // [1024]
    const float* __restrict__ bhh,            // [1024]
    const float2* __restrict__ WT2c,          // [256][1024] k-pairs
    float* __restrict__ last_out)             // [2048][256]
{
    __shared__ float xh[8][2 * CE];           // 16 KB
    const int j = threadIdx.x;
    const int wbase = blockIdx.x * 8;

    float bias[4];
    #pragma unroll
    for (int g = 0; g < 4; g++) bias[g] = bih[g * CE + j] + bhh[g * CE + j];

    int len[8];
    float c[8];
    #pragma unroll
    for (int w = 0; w < 8; w++) {
        c[w] = 0.0f;
        xh[w][CE + j] = 0.0f;                 // h_{-1} = 0
        len[w] = char_lens[wbase + w];
    }

    for (int t = 0; t < LMAX; t++) {
        #pragma unroll
        for (int w = 0; w < 8; w++) {
            int ci = char_idxs[(wbase + w) * LMAX + t];
            xh[w][j] = char_emb[ci * CE + j];
        }
        __syncthreads();

        float acc[4][8];
        #pragma unroll
        for (int g = 0; g < 4; g++)
            #pragma unroll
            for (int w = 0; w < 8; w++) acc[g][w] = 0.0f;

        for (int kp = 0; kp < CE; kp++) {     // 256 pairs over K=512
            float2 wv[4];
            #pragma unroll
            for (int g = 0; g < 4; g++) wv[g] = WT2c[kp * GC + g * CE + j];
            #pragma unroll
            for (int w = 0; w < 8; w++) {
                float2 xv = *(const float2*)&xh[w][2 * kp];
                #pragma unroll
                for (int g = 0; g < 4; g++)
                    acc[g][w] = fmaf(wv[g].y, xv.y, fmaf(wv[g].x, xv.x, acc[g][w]));
            }
        }
        __syncthreads();                      // all reads of xh done

        #pragma unroll
        for (int w = 0; w < 8; w++) {
            float iv = sigm(acc[0][w] + bias[0]);
            float fv = sigm(acc[1][w] + bias[1]);
            float gv = tanhf(acc[2][w] + bias[2]);
            float ov = sigm(acc[3][w] + bias[3]);
            c[w] = fv * c[w] + iv * gv;
            float h = ov * tanhf(c[w]);
            xh[w][CE + j] = h;
            if (t == len[w] - 1) last_out[(wbase + w) * CE + j] = h;
        }
    }
}

// ---------- word-LSTM input gates GEMM: in_gates = [we|last] @ Wih_w^T + bias ----------
__global__ void __launch_bounds__(256) wordin_kernel(
    const int* __restrict__ word_idxs,
    const float* __restrict__ word_emb,          // [50000][512]
    const float* __restrict__ last,              // [2048][256]
    const float2* __restrict__ WT2w,             // [384][4096] k-pairs
    const float* __restrict__ bih,               // [4096]
    const float* __restrict__ bhh,               // [4096]
    float* __restrict__ in_gates)                // [2048][4096]
{
    __shared__ float xh[8][KW];                  // 24 KB
    const int j = threadIdx.x;
    const int wbase = (blockIdx.x & 255) * 8;
    const int rb = blockIdx.x >> 8;              // 0..3

    for (int w = 0; w < 8; w++) {
        int wi = word_idxs[wbase + w];
        xh[w][j]        = word_emb[wi * WE + j];
        xh[w][CE + j]   = word_emb[wi * WE + CE + j];
        xh[w][WE + j]   = last[(wbase + w) * CE + j];
    }
    __syncthreads();

    float acc[4][8];
    #pragma unroll
    for (int g = 0; g < 4; g++)
        #pragma unroll
        for (int w = 0; w < 8; w++) acc[g][w] = 0.0f;

    for (int kp = 0; kp < KW / 2; kp++) {        // 384 pairs
        float2 wv[4];
        #pragma unroll
        for (int g = 0; g < 4; g++) wv[g] = WT2w[kp * GW + rb * GC + g * CE + j];
        #pragma unroll
        for (int w = 0; w < 8; w++) {
            float2 xv = *(const float2*)&xh[w][2 * kp];
            #pragma unroll
            for (int g = 0; g < 4; g++)
                acc[g][w] = fmaf(wv[g].y, xv.y, fmaf(wv[g].x, xv.x, acc[g][w]));
        }
    }

    #pragma unroll
    for (int g = 0; g < 4; g++) {
        int row = rb * GC + g * CE + j;
        float bias = bih[row] + bhh[row];
        #pragma unroll
        for (int w = 0; w < 8; w++)
            in_gates[(wbase + w) * GW + row] = acc[g][w] + bias;
    }
}

// ---------- persistent word-LSTM recurrence (v4) ----------
// 128 WGs x 512 thr (8 waves). Wave v of WG w owns hidden unit w*8+v; lane l holds
// Whh[g*H+unit][i*256+4l..+3] for g,i in 0..3 => 64 weights pinned into AGPRs
// (constraint "a": allocator cannot spill; gfx950 unified RF, VALU reads AGPR).
// Sync: tagged {tag=t+1 | h} u64 relaxed agent atomics in a 3-slot ring (data IS the
// flag; no fences => L2 never invalidated). Each wave polls its 128-entry slice
// (2 u64/lane) and fills its LDS slice; one barrier/step.
// out written COALESCED by rotating WG (t-1)&127 from the LDS h broadcast — no
// scattered 4-B stores (they caused ~130 MB of partial-line RMW fetch in r4).
__global__ void __launch_bounds__(512, 2) word_rnn_kernel(
    const float* __restrict__ Whh,            // [4096][1024]
    const float* __restrict__ in_gates,       // [2048][4096]
    unsigned long long* __restrict__ ring,    // [3][1024] tagged h (slot0+tags zeroed)
    float* __restrict__ out)                  // [2048][1024]
{
    const int tid = threadIdx.x;
    const int v = tid >> 6;                   // wave id 0..7
    const int l = tid & 63;                   // lane
    const int unit = blockIdx.x * 8 + v;      // hidden unit owned by this wave

    __shared__ float hbb[2][HDIM];            // 8 KB, double-buffered h broadcast

    // resident weights: w[g][i*4+e] = Whh[g*H+unit][i*256 + l*4 + e] (coalesced loads)
    float wr[4][16];
    #pragma unroll
    for (int i = 0; i < 4; i++) {
        #pragma unroll
        for (int g = 0; g < 4; g++) {
            f32x4 q = *(const f32x4*)(Whh + (size_t)(g * HDIM + unit) * HDIM + i * 256 + l * 4);
            wr[g][i * 4 + 0] = q[0]; wr[g][i * 4 + 1] = q[1];
            wr[g][i * 4 + 2] = q[2]; wr[g][i * 4 + 3] = q[3];
        }
    }
    // pin every scalar into an AGPR — guaranteed resident, not spillable
    #pragma unroll
    for (int g = 0; g < 4; g++)
        #pragma unroll
        for (int e = 0; e < 16; e++)
            asm volatile("" : "+a"(wr[g][e]));

    float c_reg = 0.0f;

    for (int t = 0; t <= S_WORDS; t++) {      // t==S_WORDS: poll-only epilogue (flush out)
        // prefetch this step's input-gate contributions (lane 0 of each wave)
        float ing0 = 0.f, ing1 = 0.f, ing2 = 0.f, ing3 = 0.f;
        if (l == 0 && t < S_WORDS) {
            const float* ig = in_gates + (size_t)t * GW + unit;
            ing0 = ig[0 * HDIM]; ing1 = ig[1 * HDIM];
            ing2 = ig[2 * HDIM]; ing3 = ig[3 * HDIM];
        }

        // distributed poll: wave v owns ring slice [v*128, v*128+128)
        const unsigned long long* slot = ring + (t % 3) * HDIM + v * 128;
        unsigned long long a0, a1;
        for (;;) {
            a0 = __hip_atomic_load(slot + l,      __ATOMIC_RELAXED, __HIP_MEMORY_SCOPE_AGENT);
            a1 = __hip_atomic_load(slot + 64 + l, __ATOMIC_RELAXED, __HIP_MEMORY_SCOPE_AGENT);
            bool ok = ((unsigned)(a0 >> 32) == (unsigned)t) &&
                      ((unsigned)(a1 >> 32) == (unsigned)t);
            if (__all(ok)) break;
        }
        {
            union { unsigned u32; float f; } c0, c1;
            c0.u32 = (unsigned)a0; c1.u32 = (unsigned)a1;
            hbb[t & 1][v * 128 + l]      = c0.f;
            hbb[t & 1][v * 128 + 64 + l] = c1.f;
        }
        __syncthreads();

        if (t < S_WORDS) {
            // gates[g] = sum_k Whh[g*H+unit][k] * h[k]; lane l covers k in {i*256+4l..+3}
            float acc0 = 0.f, acc1 = 0.f, acc2 = 0.f, acc3 = 0.f;
            #pragma unroll
            for (int i = 0; i < 4; i++) {
                f32x4 hv = *(const f32x4*)&hbb[t & 1][i * 256 + l * 4];
                #pragma unroll
                for (int e = 0; e < 4; e++) {
                    acc0 = fmaf(wr[0][i * 4 + e], hv[e], acc0);
                    acc1 = fmaf(wr[1][i * 4 + e], hv[e], acc1);
                    acc2 = fmaf(wr[2][i * 4 + e], hv[e], acc2);
                    acc3 = fmaf(wr[3][i * 4 + e], hv[e], acc3);
                }
            }
            // full-wave butterfly: lane 0 ends with the 4 gate sums
            #pragma unroll
            for (int off = 32; off >= 1; off >>= 1) {
                acc0 += __shfl_xor(acc0, off, 64);
                acc1 += __shfl_xor(acc1, off, 64);
                acc2 += __shfl_xor(acc2, off, 64);
                acc3 += __shfl_xor(acc3, off, 64);
            }

            if (l == 0) {
                float iv = sigm(acc0 + ing0);
                float fv = sigm(acc1 + ing1);
                float gv = tanh_fast(acc2 + ing2);
                float ov = sigm(acc3 + ing3);
                c_reg = fv * c_reg + iv * gv;
                float h = ov * tanh_fast(c_reg);
                union { float f; unsigned u32; } cv; cv.f = h;
                unsigned long long pv =
                    ((unsigned long long)(unsigned)(t + 1) << 32) | (unsigned long long)cv.u32;
                __hip_atomic_store(ring + ((t + 1) % 3) * HDIM + unit, pv,
                                   __ATOMIC_RELAXED, __HIP_MEMORY_SCOPE_AGENT);
            }
        }

        // coalesced out: rotating WG writes the PREVIOUS row (hbb[t&1] == h_{t-1})
        if (t >= 1 && blockIdx.x == (unsigned)((t - 1) & (NWG - 1))) {
            float2 hv = *(const float2*)&hbb[t & 1][tid * 2];
            *(float2*)(out + (size_t)(t - 1) * HDIM + tid * 2) = hv;
        }
        // no trailing barrier: next LDS write targets the other buffer; a
        // two-step-later overwrite is ordered by the intervening per-step barrier
        // (ds_reads of this buffer retire before each wave's next-step ds ops)
    }
}

extern "C" void kernel_launch(void* const* d_in, const int* in_sizes, int n_in,
                              void* d_out, int out_size, void* d_ws, size_t ws_size,
                              hipStream_t stream) {
    const int* word_idxs = (const int*)d_in[0];
    const int* char_idxs = (const int*)d_in[1];
    const int* char_lens = (const int*)d_in[2];
    const float* char_emb = (const float*)d_in[3];
    const float* word_emb = (const float*)d_in[4];
    const float* Wih_c = (const float*)d_in[5];
    const float* Whh_c = (const float*)d_in[6];
    const float* bih_c = (const float*)d_in[7];
    const float* bhh_c = (const float*)d_in[8];
    const float* Wih_w = (const float*)d_in[9];
    const float* Whh_w = (const float*)d_in[10];
    const float* bih_w = (const float*)d_in[11];
    const float* bhh_w = (const float*)d_in[12];

    char* ws = (char*)d_ws;
    float*  in_gates = (float*)(ws + IN_GATES_OFF);
    float*  last     = (float*)(ws + LAST_OFF);
    float2* WT2c     = (float2*)(ws + WT2C_OFF);
    float2* WT2w     = (float2*)(ws + WT2W_OFF);
    unsigned long long* ring = (unsigned long long*)(ws + RING_OFF);

    hipLaunchKernelGGL(prep_c_kernel, dim3(1024), dim3(256), 0, stream,
                       Wih_c, Whh_c, WT2c);
    hipLaunchKernelGGL(prep_w_kernel, dim3(6144), dim3(256), 0, stream,
                       Wih_w, WT2w);
    hipLaunchKernelGGL(char_lstm_kernel, dim3(256), dim3(256), 0, stream,
                       char_idxs, char_lens, char_emb, bih_c, bhh_c, WT2c, last);
    // ring aliases WT2c — zero it only after char_lstm has consumed the weights.
    // slot0 = {h=0, tag=0} (valid t=0 input); slots 1/2 tag=0 != expected t -> not ready
    hipMemsetAsync(ws + RING_OFF, 0, 3 * HDIM * sizeof(unsigned long long), stream);
    hipLaunchKernelGGL(wordin_kernel, dim3(1024), dim3(256), 0, stream,
                       word_idxs, word_emb, last, WT2w, bih_w, bhh_w, in_gates);
    hipLaunchKernelGGL(word_rnn_kernel, dim3(NWG), dim3(512), 0, stream,
                       Whh_w, in_gates, ring, (float*)d_out);
}

// Round 6
// 6870.526 us; speedup vs baseline: 1.2293x; 1.2293x over previous
//
#include <hip/hip_runtime.h>
#include <hip/hip_bf16.h>
#include <stdint.h>

// Problem constants (from reference)
#define S_WORDS 2048
#define LMAX    16
#define CE      256
#define WE      512
#define HDIM    1024
#define GC      1024   // 4*CE
#define GW      4096   // 4*HDIM
#define KW      768    // WE + CE
#define NWG     256    // persistent workgroups for word recurrence (1/CU)

// Workspace layout (bytes) — high-water 50,331,648 (48 MiB)
#define IN_GATES_OFF 0                       // 2048*4096 fp32 = 33554432
#define LAST_OFF     33554432                // 2048*256 fp32  =  2097152
#define WT2C_OFF     35651584                // 256*1024 float2 = 2097152 (char weights)
#define WT2W_OFF     37748736                // 384*4096 float2 = 12582912
// Ring aliases WT2c (dead after char_lstm; memset enqueued after char_lstm):
#define RING_OFF     WT2C_OFF                // 3 slots * 1024 u64 = 24576

typedef float f32x4 __attribute__((ext_vector_type(4)));

static __device__ __forceinline__ float sigm(float x) { return 1.0f / (1.0f + __expf(-x)); }
// fast tanh: (e^{2|x|}-1)/(e^{2|x|}+1) with sign restore; clamp avoids inf/inf
static __device__ __forceinline__ float tanh_fast(float x) {
    float ax = fminf(fabsf(x), 15.0f);
    float e  = __expf(2.0f * ax);
    float t  = (e - 1.0f) / (e + 1.0f);
    return copysignf(t, x);
}

// ---------- prep: transposed k-major float2 pairs for coalesced reads ----------
__global__ void prep_c_kernel(const float* __restrict__ Wih,
                              const float* __restrict__ Whh,
                              float2* __restrict__ WT2c) {
    int idx = blockIdx.x * blockDim.x + threadIdx.x;   // 256*1024
    if (idx >= 256 * GC) return;
    int kp = idx >> 10, row = idx & (GC - 1);
    int k = kp * 2;
    float2 v;
    if (k < CE) { v.x = Wih[row * CE + k];      v.y = Wih[row * CE + k + 1]; }
    else        { v.x = Whh[row * CE + k - CE]; v.y = Whh[row * CE + k - CE + 1]; }
    WT2c[idx] = v;
}

__global__ void prep_w_kernel(const float* __restrict__ Wih,
                              float2* __restrict__ WT2w) {
    int idx = blockIdx.x * blockDim.x + threadIdx.x;   // 384*4096
    if (idx >= 384 * GW) return;
    int kp = idx >> 12, row = idx & (GW - 1);
    float2 v;
    v.x = Wih[row * KW + 2 * kp];
    v.y = Wih[row * KW + 2 * kp + 1];
    WT2w[idx] = v;
}

// ---------- char LSTM: 256 blocks x 256 threads; block handles 8 words ----------
__global__ void __launch_bounds__(256) char_lstm_kernel(
    const int* __restrict__ char_idxs,        // [2048][16]
    const int* __restrict__ char_lens,        // [2048]
    const float* __restrict__ char_emb,       // [256][256]
    const float* __restrict__ bih,            // [1024]
    const float* __restrict__ bhh,            // [1024]
    const float2* __restrict__ WT2c,          // [256][1024] k-pairs
    float* __restrict__ last_out)             // [2048][256]
{
    __shared__ float xh[8][2 * CE];           // 16 KB
    const int j = threadIdx.x;
    const int wbase = blockIdx.x * 8;

    float bias[4];
    #pragma unroll
    for (int g = 0; g < 4; g++) bias[g] = bih[g * CE + j] + bhh[g * CE + j];

    int len[8];
    float c[8];
    #pragma unroll
    for (int w = 0; w < 8; w++) {
        c[w] = 0.0f;
        xh[w][CE + j] = 0.0f;                 // h_{-1} = 0
        len[w] = char_lens[wbase + w];
    }

    for (int t = 0; t < LMAX; t++) {
        #pragma unroll
        for (int w = 0; w < 8; w++) {
            int ci = char_idxs[(wbase + w) * LMAX + t];
            xh[w][j] = char_emb[ci * CE + j];
        }
        __syncthreads();

        float acc[4][8];
        #pragma unroll
        for (int g = 0; g < 4; g++)
            #pragma unroll
            for (int w = 0; w < 8; w++) acc[g][w] = 0.0f;

        for (int kp = 0; kp < CE; kp++) {     // 256 pairs over K=512
            float2 wv[4];
            #pragma unroll
            for (int g = 0; g < 4; g++) wv[g] = WT2c[kp * GC + g * CE + j];
            #pragma unroll
            for (int w = 0; w < 8; w++) {
                float2 xv = *(const float2*)&xh[w][2 * kp];
                #pragma unroll
                for (int g = 0; g < 4; g++)
                    acc[g][w] = fmaf(wv[g].y, xv.y, fmaf(wv[g].x, xv.x, acc[g][w]));
            }
        }
        __syncthreads();                      // all reads of xh done

        #pragma unroll
        for (int w = 0; w < 8; w++) {
            float iv = sigm(acc[0][w] + bias[0]);
            float fv = sigm(acc[1][w] + bias[1]);
            float gv = tanhf(acc[2][w] + bias[2]);
            float ov = sigm(acc[3][w] + bias[3]);
            c[w] = fv * c[w] + iv * gv;
            float h = ov * tanhf(c[w]);
            xh[w][CE + j] = h;
            if (t == len[w] - 1) last_out[(wbase + w) * CE + j] = h;
        }
    }
}

// ---------- word-LSTM input gates GEMM: in_gates = [we|last] @ Wih_w^T + bias ----------
__global__ void __launch_bounds__(256) wordin_kernel(
    const int* __restrict__ word_idxs,
    const float* __restrict__ word_emb,          // [50000][512]
    const float* __restrict__ last,              // [2048][256]
    const float2* __restrict__ WT2w,             // [384][4096] k-pairs
    const float* __restrict__ bih,               // [4096]
    const float* __restrict__ bhh,               // [4096]
    float* __restrict__ in_gates)                // [2048][4096]
{
    __shared__ float xh[8][KW];                  // 24 KB
    const int j = threadIdx.x;
    const int wbase = (blockIdx.x & 255) * 8;
    const int rb = blockIdx.x >> 8;              // 0..3

    for (int w = 0; w < 8; w++) {
        int wi = word_idxs[wbase + w];
        xh[w][j]        = word_emb[wi * WE + j];
        xh[w][CE + j]   = word_emb[wi * WE + CE + j];
        xh[w][WE + j]   = last[(wbase + w) * CE + j];
    }
    __syncthreads();

    float acc[4][8];
    #pragma unroll
    for (int g = 0; g < 4; g++)
        #pragma unroll
        for (int w = 0; w < 8; w++) acc[g][w] = 0.0f;

    for (int kp = 0; kp < KW / 2; kp++) {        // 384 pairs
        float2 wv[4];
        #pragma unroll
        for (int g = 0; g < 4; g++) wv[g] = WT2w[kp * GW + rb * GC + g * CE + j];
        #pragma unroll
        for (int w = 0; w < 8; w++) {
            float2 xv = *(const float2*)&xh[w][2 * kp];
            #pragma unroll
            for (int g = 0; g < 4; g++)
                acc[g][w] = fmaf(wv[g].y, xv.y, fmaf(wv[g].x, xv.x, acc[g][w]));
        }
    }

    #pragma unroll
    for (int g = 0; g < 4; g++) {
        int row = rb * GC + g * CE + j;
        float bias = bih[row] + bhh[row];
        #pragma unroll
        for (int w = 0; w < 8; w++)
            in_gates[(wbase + w) * GW + row] = acc[g][w] + bias;
    }
}

// ---------- persistent word-LSTM recurrence (v6: 256 WGs, 32 weights/lane) ----------
// 256 WGs x 512 thr (8 waves, 1 WG/CU). WG b owns units [4b,4b+4).
// Wave v handles unit 4b+(v&3), k-half (v>>2): 4 gates x 512 k / 64 lanes =
// 32 weights/lane (8 f32x4) — small enough to stay VGPR-resident (no spill,
// no AGPR, no per-step scratch reload from L2; that reload was ~0.5-1 us/step in r4).
// Sync: tagged {tag=t+1 | h} u64 relaxed agent atomics, 3-slot ring, no fences.
// Each wave polls its 128-entry slice (2 u64/lane) and fills its LDS slice.
// Cross-wave combine (k-halves + 4 gates) via 128-B LDS exchange + 2nd barrier;
// elementwise + publish by wave-0 lanes 0..3 (4 adjacent u64 publishes = one
// 32-B sector per WG).
__global__ void __launch_bounds__(512, 2) word_rnn_kernel(
    const float* __restrict__ Whh,            // [4096][1024]
    const float* __restrict__ in_gates,       // [2048][4096]
    unsigned long long* __restrict__ ring,    // [3][1024] tagged h (slot0+tags zeroed)
    float* __restrict__ out)                  // [2048][1024]
{
    const int tid   = threadIdx.x;
    const int v     = tid >> 6;               // wave id 0..7
    const int l     = tid & 63;               // lane
    const int ul    = v & 3;                  // local unit 0..3
    const int kappa = v >> 2;                 // k-half 0/1
    const int unit  = blockIdx.x * 4 + ul;

    __shared__ float hbb[2][HDIM];            // 8 KB, double-buffered h broadcast
    __shared__ float gex[2][4][4];            // [kappa][local unit][gate] partial sums

    // resident weights: w[g][i] = Whh[g*H+unit][kappa*512 + i*256 + l*4 .. +3]
    f32x4 w[4][2];
    #pragma unroll
    for (int g = 0; g < 4; g++)
        #pragma unroll
        for (int i = 0; i < 2; i++)
            w[g][i] = *(const f32x4*)(Whh + (size_t)(g * HDIM + unit) * HDIM
                                      + kappa * 512 + i * 256 + l * 4);
    // light pin: opaque def discourages re-load sinking; only 8 f32x4 -> no spill pressure
    #pragma unroll
    for (int g = 0; g < 4; g++)
        #pragma unroll
        for (int i = 0; i < 2; i++)
            asm volatile("" : "+v"(w[g][i]));

    float c_reg = 0.0f;                       // live in wave-0 lanes 0..3 only

    for (int t = 0; t < S_WORDS; t++) {
        // prefetch input-gate contributions (wave-0 lanes 0..3), off critical path
        float ing0 = 0.f, ing1 = 0.f, ing2 = 0.f, ing3 = 0.f;
        if (tid < 4) {
            const float* ig = in_gates + (size_t)t * GW + blockIdx.x * 4 + tid;
            ing0 = ig[0 * HDIM]; ing1 = ig[1 * HDIM];
            ing2 = ig[2 * HDIM]; ing3 = ig[3 * HDIM];
        }

        // distributed poll: wave v owns ring slice [v*128, v*128+128)
        const unsigned long long* slot = ring + (t % 3) * HDIM + v * 128;
        unsigned long long a0, a1;
        for (;;) {
            a0 = __hip_atomic_load(slot + l,      __ATOMIC_RELAXED, __HIP_MEMORY_SCOPE_AGENT);
            a1 = __hip_atomic_load(slot + 64 + l, __ATOMIC_RELAXED, __HIP_MEMORY_SCOPE_AGENT);
            bool ok = ((unsigned)(a0 >> 32) == (unsigned)t) &&
                      ((unsigned)(a1 >> 32) == (unsigned)t);
            if (__all(ok)) break;
        }
        {
            union { unsigned u32; float f; } c0, c1;
            c0.u32 = (unsigned)a0; c1.u32 = (unsigned)a1;
            hbb[t & 1][v * 128 + l]      = c0.f;
            hbb[t & 1][v * 128 + 64 + l] = c1.f;
        }
        __syncthreads();                      // barrier 1: h broadcast complete

        // partial gates over this wave's k-half: 32 FMA/lane
        float acc0 = 0.f, acc1 = 0.f, acc2 = 0.f, acc3 = 0.f;
        #pragma unroll
        for (int i = 0; i < 2; i++) {
            f32x4 hv = *(const f32x4*)&hbb[t & 1][kappa * 512 + i * 256 + l * 4];
            #pragma unroll
            for (int e = 0; e < 4; e++) {
                acc0 = fmaf(w[0][i][e], hv[e], acc0);
                acc1 = fmaf(w[1][i][e], hv[e], acc1);
                acc2 = fmaf(w[2][i][e], hv[e], acc2);
                acc3 = fmaf(w[3][i][e], hv[e], acc3);
            }
        }
        #pragma unroll
        for (int off = 32; off >= 1; off >>= 1) {
            acc0 += __shfl_xor(acc0, off, 64);
            acc1 += __shfl_xor(acc1, off, 64);
            acc2 += __shfl_xor(acc2, off, 64);
            acc3 += __shfl_xor(acc3, off, 64);
        }
        if (l == 0) {
            gex[kappa][ul][0] = acc0; gex[kappa][ul][1] = acc1;
            gex[kappa][ul][2] = acc2; gex[kappa][ul][3] = acc3;
        }
        __syncthreads();                      // barrier 2: partials exchanged

        if (tid < 4) {                        // wave-0 lane tid -> unit 4b+tid
            float gi = gex[0][tid][0] + gex[1][tid][0] + ing0;
            float gf = gex[0][tid][1] + gex[1][tid][1] + ing1;
            float gg = gex[0][tid][2] + gex[1][tid][2] + ing2;
            float go = gex[0][tid][3] + gex[1][tid][3] + ing3;
            float iv = sigm(gi);
            float fv = sigm(gf);
            float gv = tanh_fast(gg);
            float ov = sigm(go);
            c_reg = fv * c_reg + iv * gv;
            float h = ov * tanh_fast(c_reg);
            union { float f; unsigned u32; } cv; cv.f = h;
            unsigned long long pv =
                ((unsigned long long)(unsigned)(t + 1) << 32) | (unsigned long long)cv.u32;
            // publish FIRST (critical path); 4 adjacent u64 = one 32-B sector
            __hip_atomic_store(ring + ((t + 1) % 3) * HDIM + blockIdx.x * 4 + tid, pv,
                               __ATOMIC_RELAXED, __HIP_MEMORY_SCOPE_AGENT);
            out[(size_t)t * HDIM + blockIdx.x * 4 + tid] = h;  // row fully tiled by WGs
        }
        // no trailing barrier: next step writes the other hbb buffer; gex(t+1)
        // writes happen only after barrier 1 of t+1, which wave 0 reaches after
        // its gex reads here.
    }
}

extern "C" void kernel_launch(void* const* d_in, const int* in_sizes, int n_in,
                              void* d_out, int out_size, void* d_ws, size_t ws_size,
                              hipStream_t stream) {
    const int* word_idxs = (const int*)d_in[0];
    const int* char_idxs = (const int*)d_in[1];
    const int* char_lens = (const int*)d_in[2];
    const float* char_emb = (const float*)d_in[3];
    const float* word_emb = (const float*)d_in[4];
    const float* Wih_c = (const float*)d_in[5];
    const float* Whh_c = (const float*)d_in[6];
    const float* bih_c = (const float*)d_in[7];
    const float* bhh_c = (const float*)d_in[8];
    const float* Wih_w = (const float*)d_in[9];
    const float* Whh_w = (const float*)d_in[10];
    const float* bih_w = (const float*)d_in[11];
    const float* bhh_w = (const float*)d_in[12];

    char* ws = (char*)d_ws;
    float*  in_gates = (float*)(ws + IN_GATES_OFF);
    float*  last     = (float*)(ws + LAST_OFF);
    float2* WT2c     = (float2*)(ws + WT2C_OFF);
    float2* WT2w     = (float2*)(ws + WT2W_OFF);
    unsigned long long* ring = (unsigned long long*)(ws + RING_OFF);

    hipLaunchKernelGGL(prep_c_kernel, dim3(1024), dim3(256), 0, stream,
                       Wih_c, Whh_c, WT2c);
    hipLaunchKernelGGL(prep_w_kernel, dim3(6144), dim3(256), 0, stream,
                       Wih_w, WT2w);
    hipLaunchKernelGGL(char_lstm_kernel, dim3(256), dim3(256), 0, stream,
                       char_idxs, char_lens, char_emb, bih_c, bhh_c, WT2c, last);
    // ring aliases WT2c — zero it only after char_lstm has consumed the weights.
    // slot0 = {h=0, tag=0} (valid t=0 input); slots 1/2 tag=0 != expected t -> not ready
    hipMemsetAsync(ws + RING_OFF, 0, 3 * HDIM * sizeof(unsigned long long), stream);
    hipLaunchKernelGGL(wordin_kernel, dim3(1024), dim3(256), 0, stream,
                       word_idxs, word_emb, last, WT2w, bih_w, bhh_w, in_gates);
    hipLaunchKernelGGL(word_rnn_kernel, dim3(NWG), dim3(512), 0, stream,
                       Whh_w, in_gates, ring, (float*)d_out);
}